// Round 12
// baseline (1222.275 us; speedup 1.0000x reference)
//
#include <hip/hip_runtime.h>
#include <hip/hip_fp16.h>
#include <math.h>

#define NHEADS 8
#define NG 64

typedef _Float16 half8_t __attribute__((ext_vector_type(8)));
typedef _Float16 half4_t __attribute__((ext_vector_type(4)));
typedef float    float4_t __attribute__((ext_vector_type(4)));
typedef __attribute__((address_space(1))) const void g_void;
typedef __attribute__((address_space(3))) void l_void;

__device__ __forceinline__ float elu_f(float x)   { return x > 0.f ? x : expf(x) - 1.f; }
__device__ __forceinline__ float lrelu_f(float x) { return x >= 0.f ? x : 0.2f * x; }

// ---- typed 4-wide load/store + scalar converts (fp32 / fp16) ----
__device__ __forceinline__ float4 ld4(const float* p) { return *(const float4*)p; }
__device__ __forceinline__ float4 ld4(const __half* p) {
    const __half2* q = (const __half2*)p;
    __half2 a = q[0], b = q[1];
    return make_float4(__half2float(a.x), __half2float(a.y),
                       __half2float(b.x), __half2float(b.y));
}
__device__ __forceinline__ void st4(float* p, float4 v) { *(float4*)p = v; }
__device__ __forceinline__ void st4(__half* p, float4 v) {
    __half2 a, b;
    a.x = __float2half(v.x); a.y = __float2half(v.y);
    b.x = __float2half(v.z); b.y = __float2half(v.w);
    __half2* q = (__half2*)p; q[0] = a; q[1] = b;
}
__device__ __forceinline__ float scl(float v)  { return v; }
__device__ __forceinline__ float scl(__half v) { return __half2float(v); }
__device__ __forceinline__ void sst(float* p, float v)  { *p = v; }
__device__ __forceinline__ void sst(__half* p, float v) { *p = __float2half(v); }

struct h4s { __half a, b, c, d; };

// ---------------- CSR build (by dst) ----------------
__global__ void hist_kernel(const int* __restrict__ ei, int E, int Etot, int* __restrict__ counts) {
    int e = blockIdx.x * blockDim.x + threadIdx.x;
    if (e >= Etot) return;
    int dst = (e < E) ? ei[E + e] : (e - E);   // self-loop for e >= E
    atomicAdd(&counts[dst], 1);
}

// single-block shuffle scan, 1024 elems/iter, 2 barriers/iter
__global__ __launch_bounds__(256) void scan_kernel(const int* __restrict__ counts,
                                                   int* __restrict__ offsets,
                                                   int* __restrict__ cursor, int N) {
    __shared__ int wsum[4];
    const int tid = threadIdx.x;
    const int lane = tid & 63, wid = tid >> 6;
    int carry = 0;
    for (int base = 0; base < N; base += 1024) {
        int i0 = base + tid * 4;
        int v0 = 0, v1 = 0, v2 = 0, v3 = 0;
        if (i0 + 3 < N) {
            int4 q = *(const int4*)(counts + i0);
            v0 = q.x; v1 = q.y; v2 = q.z; v3 = q.w;
        } else {
            if (i0     < N) v0 = counts[i0];
            if (i0 + 1 < N) v1 = counts[i0 + 1];
            if (i0 + 2 < N) v2 = counts[i0 + 2];
            if (i0 + 3 < N) v3 = counts[i0 + 3];
        }
        int tsum = v0 + v1 + v2 + v3;
        int incl = tsum;
#pragma unroll
        for (int off = 1; off < 64; off <<= 1) {
            int t = __shfl_up(incl, off);
            if (lane >= off) incl += t;
        }
        if (lane == 63) wsum[wid] = incl;
        __syncthreads();
        int woff = carry;
        for (int w = 0; w < wid; ++w) woff += wsum[w];
        int o0 = woff + incl - tsum;
        int o1 = o0 + v0, o2 = o1 + v1, o3 = o2 + v2;
        if (i0     < N) { offsets[i0]     = o0; cursor[i0]     = o0; }
        if (i0 + 1 < N) { offsets[i0 + 1] = o1; cursor[i0 + 1] = o1; }
        if (i0 + 2 < N) { offsets[i0 + 2] = o2; cursor[i0 + 2] = o2; }
        if (i0 + 3 < N) { offsets[i0 + 3] = o3; cursor[i0 + 3] = o3; }
        __syncthreads();
        carry += wsum[0] + wsum[1] + wsum[2] + wsum[3];
    }
    if (tid == 0) offsets[N] = carry;
}

__global__ void scatter_kernel(const int* __restrict__ ei, int E, int Etot,
                               int* __restrict__ cursor, int* __restrict__ perm_src) {
    int e = blockIdx.x * blockDim.x + threadIdx.x;
    if (e >= Etot) return;
    int src, dst;
    if (e < E) { src = ei[e]; dst = ei[E + e]; }
    else       { src = e - E; dst = e - E; }
    int pos = atomicAdd(&cursor[dst], 1);
    perm_src[pos] = src;
}

// ---------------- fused prep: x->fp16 convert + 5 weight transposes ----------------
struct PrepArgs {
    const float* x; __half* x16; long n4;
    const float* W[5]; __half* T[5];
    int K[5], Nn[5];
    int b0;          // end of convert stage
    int tb[5];       // cumulative ends of transpose stages
};

__global__ __launch_bounds__(256) void prep_kernel(PrepArgs a) {
    int bid = blockIdx.x;
    if (bid < a.b0) {
        long i = (long)bid * 256 + threadIdx.x;
        if (i < a.n4) {
            float4 v = ((const float4*)a.x)[i];
            h4s o; o.a = __float2half(v.x); o.b = __float2half(v.y);
            o.c = __float2half(v.z); o.d = __float2half(v.w);
            ((h4s*)a.x16)[i] = o;
        }
        return;
    }
    int l = 0, base = a.b0;
#pragma unroll
    for (int j = 0; j < 4; ++j) if (bid >= a.tb[j]) { l = j + 1; base = a.tb[j]; }
    const float* W = a.W[l]; __half* T = a.T[l];
    int K = a.K[l], Nn = a.Nn[l];
    int t = bid - base;
    int tilesx = Nn >> 5;
    int nb = (t % tilesx) * 32, kb = (t / tilesx) * 32;
    __shared__ float tt[32][33];
    int tx = threadIdx.x & 31, ty = threadIdx.x >> 5;
#pragma unroll
    for (int r = 0; r < 32; r += 8)
        tt[ty + r][tx] = W[(size_t)(kb + ty + r) * Nn + nb + tx];
    __syncthreads();
#pragma unroll
    for (int r = 0; r < 32; r += 8)
        T[(size_t)(nb + ty + r) * K + kb + tx] = __float2half(tt[tx][ty + r]);
}

// ---------------- 256x256 8-wave counted-vmcnt MFMA GEMM (R9 schedule) ----
// C[M][N] = A[M][K] @ Bt[N][K]^T, fp16 in, fp16 out, fp32 acc.
// BK=64, double-buffered LDS (128 KiB), 4 phases/K-tile (phase = C-quadrant),
// stage FIFO {A-lo,B-lo,B-hi,A-hi}, vmcnt(6) before P1/P2/P3 — the R9 verified
// schedule (184 us, MfmaUtil 40%). R10's coarse 1-wait variant regressed.
// FUSE_AL epilogue (R12): partials go to a DEDICATED al_sm (disjoint from the
// staging LDS -> no vmcnt(0) drain of the trailing garbage prefetch), one raw
// lgkmcnt(0)+s_barrier instead of two __syncthreads, and [k][wc][row] layout so
// the final pass reads stride-1 (R11 had 20000 bank conflicts + 2 full drains).
#define MMA_PHASE(MH, NH)                                                      \
  __builtin_amdgcn_s_setprio(1);                                               \
  { _Pragma("unroll") for (int f_ = 0; f_ < 4; ++f_) {                         \
      _Pragma("unroll") for (int g_ = 0; g_ < 2; ++g_) {                       \
        _Pragma("unroll") for (int kk_ = 0; kk_ < 2; ++kk_)                    \
          acc[(MH) * 2 + (NH)][f_][g_] =                                       \
              __builtin_amdgcn_mfma_f32_16x16x32_f16(                          \
                  af[f_][kk_], bf[g_][kk_],                                    \
                  acc[(MH) * 2 + (NH)][f_][g_], 0, 0, 0);                      \
  } } }                                                                        \
  __builtin_amdgcn_s_setprio(0);

template <bool FUSE_AL>
__global__ __launch_bounds__(512, 2) void gemm_mfma256_kernel(const __half* __restrict__ A,
                                                              const __half* __restrict__ Bt,
                                                              __half* __restrict__ C,
                                                              const float* __restrict__ a_src,
                                                              const float* __restrict__ a_dst,
                                                              float* __restrict__ al_s,
                                                              float* __restrict__ al_d,
                                                              int M, int N, int K) {
    __shared__ __half lds[2][2][16384];   // [buf][A=0/B=1][256*64]
    const int tid  = threadIdx.x;
    const int lane = tid & 63;
    const int wave = tid >> 6;            // 0..7
    const int wr   = wave >> 2;           // 0..1 (row half within quadrant)
    const int wc   = wave & 3;            // 0..3 (col quarter within quadrant)

    // XCD swizzle (bijective for any nwg)
    const int nwg = (int)(gridDim.x * gridDim.y);
    const int lin = (int)(blockIdx.y * gridDim.x + blockIdx.x);
    const int q = nwg >> 3, r = nwg & 7;
    const int xcd = lin & 7, idx = lin >> 3;
    const int nid = (xcd < r ? xcd * (q + 1) : r * (q + 1) + (xcd - r) * q) + idx;
    const int bx = nid % (int)gridDim.x;
    const int by = nid / (int)gridDim.x;
    const int row0 = by * 256;
    const int col0 = bx * 256;

    const int l15 = lane & 15, l4 = lane >> 4;
    const int srow = tid >> 3;                     // 0..63
    const int kch  = (tid & 7) ^ (srow & 7);       // XOR involution (stage source)

    float4_t acc[4][4][2];   // [quadrant mh*2+nh][m-frag][n-frag]
#pragma unroll
    for (int i = 0; i < 4; ++i)
#pragma unroll
        for (int j = 0; j < 4; ++j)
#pragma unroll
            for (int g = 0; g < 2; ++g)
                acc[i][j][g] = (float4_t){0.f, 0.f, 0.f, 0.f};

    // stage one half-tile (128 rows x 64 k) = 2 x global_load_lds per thread
    auto stageA = [&](int cb, int kt, int halfsel) {
#pragma unroll
        for (int sub = 0; sub < 2; ++sub) {
            int rr = halfsel * 128 + sub * 64 + srow;
            int gr = row0 + rr; if (gr >= M) gr = M - 1;    // clamp (stores guarded)
            const __half* g = A + (size_t)gr * K + kt * 64 + kch * 8;
            __half* l = &lds[cb][0][(halfsel * 128 + sub * 64) * 64] + tid * 8;
            __builtin_amdgcn_global_load_lds((g_void*)g, (l_void*)l, 16, 0, 0);
        }
    };
    auto stageB = [&](int cb, int kt, int halfsel) {
#pragma unroll
        for (int sub = 0; sub < 2; ++sub) {
            int rr = halfsel * 128 + sub * 64 + srow;
            const __half* g = Bt + (size_t)(col0 + rr) * K + kt * 64 + kch * 8;
            __half* l = &lds[cb][1][(halfsel * 128 + sub * 64) * 64] + tid * 8;
            __builtin_amdgcn_global_load_lds((g_void*)g, (l_void*)l, 16, 0, 0);
        }
    };

    half8_t af[4][2], bf[2][2];
    // phase-local fragment loads: quadrant (mh,nh) touches only A-half mh / B-half nh
    auto ldA = [&](int cb, int mh) {
        const char* base = (const char*)&lds[cb][0][0];
#pragma unroll
        for (int f = 0; f < 4; ++f) {
            int row = mh * 128 + wr * 64 + f * 16 + l15;   // within half mh
#pragma unroll
            for (int kk = 0; kk < 2; ++kk) {
                int ch = (kk * 4 + l4) ^ (row & 7);
                af[f][kk] = *(const half8_t*)(base + row * 128 + ch * 16);
            }
        }
    };
    auto ldB = [&](int cb, int nh) {
        const char* base = (const char*)&lds[cb][1][0];
#pragma unroll
        for (int f = 0; f < 2; ++f) {
            int row = nh * 128 + wc * 32 + f * 16 + l15;   // within half nh
#pragma unroll
            for (int kk = 0; kk < 2; ++kk) {
                int ch = (kk * 4 + l4) ^ (row & 7);
                bf[f][kk] = *(const half8_t*)(base + row * 128 + ch * 16);
            }
        }
    };

    const int nt = K >> 6;
    // prologue: tile 0 -> buf0, FIFO order A-lo, B-lo, B-hi, A-hi
    stageA(0, 0, 0); stageB(0, 0, 0); stageB(0, 0, 1); stageA(0, 0, 1);

    for (int t = 0; t < nt; ++t) {
        int cb = t & 1, nb = cb ^ 1;
        int ktn = (t + 1 < nt) ? t + 1 : t;   // last iter: clamped re-stage (never read)

        // P1: quadrant (0,0) — needs A-lo,B-lo of tile t (the 4 oldest loads)
        stageA(nb, ktn, 0);
        __builtin_amdgcn_sched_barrier(0);
        asm volatile("s_waitcnt vmcnt(6)" ::: "memory");
        __builtin_amdgcn_s_barrier();
        __builtin_amdgcn_sched_barrier(0);
        ldA(cb, 0); ldB(cb, 0);
        MMA_PHASE(0, 0)

        // P2: quadrant (0,1) — needs B-hi of tile t (af reused)
        stageB(nb, ktn, 0);
        __builtin_amdgcn_sched_barrier(0);
        asm volatile("s_waitcnt vmcnt(6)" ::: "memory");
        __builtin_amdgcn_s_barrier();
        __builtin_amdgcn_sched_barrier(0);
        ldB(cb, 1);
        MMA_PHASE(0, 1)

        // P3: quadrant (1,1) — needs A-hi of tile t (bf reused)
        stageB(nb, ktn, 1);
        __builtin_amdgcn_sched_barrier(0);
        asm volatile("s_waitcnt vmcnt(6)" ::: "memory");
        __builtin_amdgcn_s_barrier();
        __builtin_amdgcn_sched_barrier(0);
        ldA(cb, 1);
        MMA_PHASE(1, 1)

        // P4: quadrant (1,0) — all regions resident (B-lo re-read, af reused)
        stageA(nb, ktn, 1);
        ldB(cb, 0);
        MMA_PHASE(1, 0)
    }

    // C epilogue: C/D map col=lane&15, row=(lane>>4)*4+reg  [m89]
#pragma unroll
    for (int mh = 0; mh < 2; ++mh) {
#pragma unroll
        for (int nh = 0; nh < 2; ++nh) {
#pragma unroll
            for (int fm = 0; fm < 4; ++fm) {
#pragma unroll
                for (int r2 = 0; r2 < 4; ++r2) {
                    int row = row0 + mh * 128 + wr * 64 + fm * 16 + l4 * 4 + r2;
                    if (row < M) {
#pragma unroll
                        for (int fn = 0; fn < 2; ++fn) {
                            int col = col0 + nh * 128 + wc * 32 + fn * 16 + l15;
                            C[(size_t)row * N + col] = __float2half(acc[mh * 2 + nh][fm][fn][r2]);
                        }
                    }
                }
            }
        }
    }

    if constexpr (FUSE_AL) {
        // this block's 256 cols == head bx (N==2048, C==256). Compute exact
        // al_s/al_d for its rows from the fp32 accumulators.
        // Dedicated al_sm (disjoint from staging lds): the trailing garbage
        // prefetch can stay in flight — NO vmcnt(0); only lgkmcnt for LDS
        // stores. Layout [k][wc][row] -> final pass reads stride-1.
        __shared__ float al_sm[2][4][256];   // 8 KB
        const int h = bx;
        float as_v[2][2], ad_v[2][2];
#pragma unroll
        for (int nh = 0; nh < 2; ++nh)
#pragma unroll
            for (int fn = 0; fn < 2; ++fn) {
                int cc = nh * 128 + wc * 32 + fn * 16 + l15;
                as_v[nh][fn] = a_src[h * 256 + cc];
                ad_v[nh][fn] = a_dst[h * 256 + cc];
            }
#pragma unroll
        for (int mh = 0; mh < 2; ++mh)
#pragma unroll
            for (int fm = 0; fm < 4; ++fm)
#pragma unroll
                for (int r2 = 0; r2 < 4; ++r2) {
                    float ps = 0.f, pd = 0.f;
#pragma unroll
                    for (int nh = 0; nh < 2; ++nh)
#pragma unroll
                        for (int fn = 0; fn < 2; ++fn) {
                            float v = acc[mh * 2 + nh][fm][fn][r2];
                            ps += v * as_v[nh][fn];
                            pd += v * ad_v[nh][fn];
                        }
                    // reduce over the 16 lanes of this l4 group (l15 dimension)
#pragma unroll
                    for (int o = 1; o < 16; o <<= 1) {
                        ps += __shfl_xor(ps, o);
                        pd += __shfl_xor(pd, o);
                    }
                    if (l15 == 0) {
                        int rrow = mh * 128 + wr * 64 + fm * 16 + l4 * 4 + r2;
                        al_sm[0][wc][rrow] = ps;
                        al_sm[1][wc][rrow] = pd;
                    }
                }
        asm volatile("s_waitcnt lgkmcnt(0)" ::: "memory");
        __builtin_amdgcn_s_barrier();
        __builtin_amdgcn_sched_barrier(0);
        if (tid < 256) {
            int grow = row0 + tid;
            if (grow < M) {
                float s = al_sm[0][0][tid] + al_sm[0][1][tid] + al_sm[0][2][tid] + al_sm[0][3][tid];
                float d = al_sm[1][0][tid] + al_sm[1][1][tid] + al_sm[1][2][tid] + al_sm[1][3][tid];
                al_s[(size_t)grow * 8 + h] = s;
                al_d[(size_t)grow * 8 + h] = d;
            }
        }
    }
}

// ---------------- VALU GEMM (fallback path): C[M,N] = A[M,K] @ B[K,N] ----------------
template <typename TA, typename TC>
__global__ __launch_bounds__(256) void gemm_kernel(const TA* __restrict__ A,
                                                   const float* __restrict__ B,
                                                   TC* __restrict__ C,
                                                   int M, int N, int K) {
    __shared__ float As[16][64];
    __shared__ float Bs[16][64];
    const int tid  = threadIdx.x;
    const int row0 = blockIdx.y * 64, col0 = blockIdx.x * 64;
    const int am = tid >> 2, ak = (tid & 3) << 2;
    const int bk = tid >> 4, bn = (tid & 15) << 2;
    const int ty = (tid >> 4) << 2, tx = (tid & 15) << 2;
    float acc[4][4] = {};
    const int arow = row0 + am;
    for (int k0 = 0; k0 < K; k0 += 16) {
        float4 a4 = make_float4(0.f, 0.f, 0.f, 0.f);
        if (arow < M) a4 = ld4(A + (size_t)arow * K + k0 + ak);
        As[ak + 0][am] = a4.x; As[ak + 1][am] = a4.y;
        As[ak + 2][am] = a4.z; As[ak + 3][am] = a4.w;
        *(float4*)&Bs[bk][bn] = *(const float4*)(B + (size_t)(k0 + bk) * N + col0 + bn);
        __syncthreads();
#pragma unroll
        for (int k = 0; k < 16; ++k) {
            float4 ar = *(const float4*)&As[k][ty];
            float4 br = *(const float4*)&Bs[k][tx];
            acc[0][0] += ar.x * br.x; acc[0][1] += ar.x * br.y; acc[0][2] += ar.x * br.z; acc[0][3] += ar.x * br.w;
            acc[1][0] += ar.y * br.x; acc[1][1] += ar.y * br.y; acc[1][2] += ar.y * br.z; acc[1][3] += ar.y * br.w;
            acc[2][0] += ar.z * br.x; acc[2][1] += ar.z * br.y; acc[2][2] += ar.z * br.z; acc[2][3] += ar.z * br.w;
            acc[3][0] += ar.w * br.x; acc[3][1] += ar.w * br.y; acc[3][2] += ar.w * br.z; acc[3][3] += ar.w * br.w;
        }
        __syncthreads();
    }
#pragma unroll
    for (int i = 0; i < 4; ++i) {
        int r = row0 + ty + i;
        if (r < M) {
            float4 o = make_float4(acc[i][0], acc[i][1], acc[i][2], acc[i][3]);
            st4(C + (size_t)r * N + col0 + tx, o);
        }
    }
}

// ---------------- attention logits, vectorized (fp16 ht) ----------------
template <int C>
__global__ void al_vec_kernel(const __half* __restrict__ ht, const float* __restrict__ a_src,
                              const float* __restrict__ a_dst, float* __restrict__ al_s,
                              float* __restrict__ al_d, int N) {
    int wid  = (int)((blockIdx.x * blockDim.x + threadIdx.x) >> 6);
    int lane = threadIdx.x & 63;
    if (wid >= N * NHEADS) return;
    int n = wid / NHEADS, h = wid % NHEADS;
    float ss = 0.f, sd = 0.f;
    int c0 = lane * 4;
    if (c0 < C) {
        const __half* hp = ht + (size_t)n * (NHEADS * C) + h * C + c0;
        half4_t v = *(const half4_t*)hp;
        float4 as4 = *(const float4*)(a_src + h * C + c0);
        float4 ad4 = *(const float4*)(a_dst + h * C + c0);
        float v0 = (float)v[0], v1 = (float)v[1], v2 = (float)v[2], v3 = (float)v[3];
        ss = v0 * as4.x + v1 * as4.y + v2 * as4.z + v3 * as4.w;
        sd = v0 * ad4.x + v1 * ad4.y + v2 * ad4.z + v3 * ad4.w;
    }
#pragma unroll
    for (int off = 32; off > 0; off >>= 1) {
        ss += __shfl_down(ss, off);
        sd += __shfl_down(sd, off);
    }
    if (lane == 0) { al_s[wid] = ss; al_d[wid] = sd; }
}

// ---------------- aggregation with FUSED segment softmax ----------------
template <int HC, int C, int MODE>
__global__ __launch_bounds__(256) void agg_fused_kernel(const __half* __restrict__ ht,
                                                        const float* __restrict__ al_s,
                                                        const float* __restrict__ al_d,
                                                        const int* __restrict__ offsets,
                                                        const int* __restrict__ perm_src,
                                                        const float* __restrict__ bias,
                                                        void* __restrict__ outv, int N) {
    constexpr int V = HC / 256;          // 2 (HC=512) or 8 (HC=2048)
    int n = blockIdx.x;
    int tid = threadIdx.x;
    int lane = tid & 63;
    const int head = (tid * V) / C;      // constant per thread
    int s = offsets[n], e = offsets[n + 1];

    // per-wave softmax stats (redundant across the 4 waves)
    int h2 = lane & 7, es = lane >> 3;
    float ad2 = al_d[(size_t)n * 8 + h2];
    float m = -1e30f;
    for (int p0 = s + es; p0 < e; p0 += 8)
        m = fmaxf(m, lrelu_f(al_s[(size_t)perm_src[p0] * 8 + h2] + ad2));
#pragma unroll
    for (int off = 8; off < 64; off <<= 1) m = fmaxf(m, __shfl_xor(m, off));
    float den = 0.f;
    for (int p0 = s + es; p0 < e; p0 += 8)
        den += expf(lrelu_f(al_s[(size_t)perm_src[p0] * 8 + h2] + ad2) - m);
#pragma unroll
    for (int off = 8; off < 64; off <<= 1) den += __shfl_xor(den, off);
    float inv0 = 1.f / (den + 1e-16f);
    float mh   = __shfl(m, head);
    float invh = __shfl(inv0, head);
    float adh  = __shfl(ad2, head);

    float acc[V];
#pragma unroll
    for (int i = 0; i < V; ++i) acc[i] = 0.f;
    const __half* base = ht + (size_t)tid * V;
    int p = s;
    for (; p + 4 <= e; p += 4) {
        int s0 = perm_src[p], s1 = perm_src[p + 1], s2 = perm_src[p + 2], s3 = perm_src[p + 3];
        float a0 = expf(lrelu_f(al_s[(size_t)s0 * 8 + head] + adh) - mh);
        float a1 = expf(lrelu_f(al_s[(size_t)s1 * 8 + head] + adh) - mh);
        float a2 = expf(lrelu_f(al_s[(size_t)s2 * 8 + head] + adh) - mh);
        float a3 = expf(lrelu_f(al_s[(size_t)s3 * 8 + head] + adh) - mh);
        if (V == 8) {
            half8_t v0 = *(const half8_t*)(base + (size_t)s0 * HC);
            half8_t v1 = *(const half8_t*)(base + (size_t)s1 * HC);
            half8_t v2 = *(const half8_t*)(base + (size_t)s2 * HC);
            half8_t v3 = *(const half8_t*)(base + (size_t)s3 * HC);
#pragma unroll
            for (int i = 0; i < 8; ++i) acc[i] += a0 * (float)v0[i];
#pragma unroll
            for (int i = 0; i < 8; ++i) acc[i] += a1 * (float)v1[i];
#pragma unroll
            for (int i = 0; i < 8; ++i) acc[i] += a2 * (float)v2[i];
#pragma unroll
            for (int i = 0; i < 8; ++i) acc[i] += a3 * (float)v3[i];
        } else {
            __half2 w0 = *(const __half2*)(base + (size_t)s0 * HC);
            __half2 w1 = *(const __half2*)(base + (size_t)s1 * HC);
            __half2 w2 = *(const __half2*)(base + (size_t)s2 * HC);
            __half2 w3 = *(const __half2*)(base + (size_t)s3 * HC);
            acc[0] += a0 * __half2float(w0.x); acc[1] += a0 * __half2float(w0.y);
            acc[0] += a1 * __half2float(w1.x); acc[1] += a1 * __half2float(w1.y);
            acc[0] += a2 * __half2float(w2.x); acc[1] += a2 * __half2float(w2.y);
            acc[0] += a3 * __half2float(w3.x); acc[1] += a3 * __half2float(w3.y);
        }
    }
    for (; p < e; ++p) {
        int src = perm_src[p];
        float a = expf(lrelu_f(al_s[(size_t)src * 8 + head] + adh) - mh);
        const __half* hp = base + (size_t)src * HC;
        if (V == 8) {
            half8_t v = *(const half8_t*)hp;
#pragma unroll
            for (int i = 0; i < 8; ++i) acc[i] += a * (float)v[i];
        } else {
            __half2 v2 = *(const __half2*)hp;
            acc[0] += a * __half2float(v2.x);
            acc[1] += a * __half2float(v2.y);
        }
    }
    if (MODE == 0) {
        __half* out = (__half*)outv;
        if (V == 8) {
            half8_t o;
#pragma unroll
            for (int i = 0; i < 8; ++i)
                o[i] = (_Float16)elu_f(acc[i] * invh + bias[tid * 8 + i]);
            *(half8_t*)(out + (size_t)n * HC + tid * 8) = o;
        } else {
            __half2 o;
            o.x = __float2half(elu_f(acc[0] * invh + bias[tid * 2 + 0]));
            o.y = __float2half(elu_f(acc[1] * invh + bias[tid * 2 + 1]));
            *(__half2*)(out + (size_t)n * HC + tid * 2) = o;
        }
    } else {
        // V==8, C=256: LDS transpose-reduce over heads
        __shared__ float sm[256][8];
#pragma unroll
        for (int i = 0; i < 8; ++i) sm[tid][i] = acc[i] * invh;
        __syncthreads();
        float ssum = 0.f;
#pragma unroll
        for (int h = 0; h < 8; ++h) ssum += sm[h * 32 + (tid >> 3)][tid & 7];
        float* out = (float*)outv;
        out[(size_t)n * C + tid] = elu_f(ssum * (1.f / NHEADS) + bias[tid]);
    }
}

// ---------------- fallback scalar kernels (paths 0-2) ----------------
template <typename TH>
__global__ void al_kernel(const TH* __restrict__ ht, const float* __restrict__ a_src,
                          const float* __restrict__ a_dst, float* __restrict__ al_s,
                          float* __restrict__ al_d, int N, int C) {
    int wid  = (int)((blockIdx.x * blockDim.x + threadIdx.x) >> 6);
    int lane = threadIdx.x & 63;
    if (wid >= N * NHEADS) return;
    int n = wid / NHEADS, h = wid % NHEADS;
    const TH* hp = ht + (size_t)n * (NHEADS * C) + h * C;
    float ss = 0.f, sd = 0.f;
    for (int c = lane; c < C; c += 64) {
        float v = scl(hp[c]);
        ss += v * a_src[h * C + c];
        sd += v * a_dst[h * C + c];
    }
#pragma unroll
    for (int off = 32; off > 0; off >>= 1) {
        ss += __shfl_down(ss, off);
        sd += __shfl_down(sd, off);
    }
    if (lane == 0) { al_s[wid] = ss; al_d[wid] = sd; }
}

__global__ void alpha_kernel(const int* __restrict__ offsets, const int* __restrict__ perm_src,
                             const float* __restrict__ al_s, const float* __restrict__ al_d,
                             float* __restrict__ alpha, int N) {
    int idx = blockIdx.x * blockDim.x + threadIdx.x;
    if (idx >= N * NHEADS) return;
    int n = idx / NHEADS, h = idx % NHEADS;
    int s = offsets[n], e = offsets[n + 1];
    float ad = al_d[idx];
    float m = -1e30f;
    for (int p = s; p < e; ++p) {
        float v = lrelu_f(al_s[perm_src[p] * NHEADS + h] + ad);
        m = fmaxf(m, v);
    }
    float denom = 0.f;
    for (int p = s; p < e; ++p) {
        float v  = lrelu_f(al_s[perm_src[p] * NHEADS + h] + ad);
        float ex = expf(v - m);
        alpha[(size_t)p * NHEADS + h] = ex;
        denom += ex;
    }
    float inv = 1.f / (denom + 1e-16f);
    for (int p = s; p < e; ++p) alpha[(size_t)p * NHEADS + h] *= inv;
}

template <int HC, int C, int MODE, typename TH, typename TO>
__global__ __launch_bounds__(256) void agg_kernel(const TH* __restrict__ ht,
                                                  const float* __restrict__ alpha,
                                                  const int* __restrict__ offsets,
                                                  const int* __restrict__ perm_src,
                                                  const float* __restrict__ bias,
                                                  TO* __restrict__ out, int N) {
    constexpr int PER = HC / 256;
    int n = blockIdx.x;
    int tid = threadIdx.x;
    float acc[PER];
#pragma unroll
    for (int i = 0; i < PER; ++i) acc[i] = 0.f;
    int s = offsets[n], e = offsets[n + 1];
    for (int p = s; p < e; ++p) {
        int src = perm_src[p];
        const TH* hp = ht + (size_t)src * HC;
#pragma unroll
        for (int i = 0; i < PER; ++i) {
            int j = tid + i * 256;
            float a = alpha[(size_t)p * NHEADS + (j / C)];
            acc[i] += a * scl(hp[j]);
        }
    }
    if (MODE == 0) {
#pragma unroll
        for (int i = 0; i < PER; ++i) {
            int j = tid + i * 256;
            sst(&out[(size_t)n * HC + j], elu_f(acc[i] + bias[j]));
        }
    } else {
        float srow = 0.f;
#pragma unroll
        for (int i = 0; i < PER; ++i) srow += acc[i];
        sst(&out[(size_t)n * C + tid], elu_f(srow * (1.f / NHEADS) + bias[tid]));
    }
}

// ---------------- pooling (fallback path kernels) ----------------
__global__ void gstart_kernel(const int* __restrict__ batch, int* __restrict__ gstart, int N) {
    int n = blockIdx.x * blockDim.x + threadIdx.x;
    if (n > N) return;
    if (n == 0) {
        int b0 = batch[0];
        for (int g = 0; g <= b0; ++g) gstart[g] = 0;
    } else if (n == N) {
        int bl = batch[N - 1];
        for (int g = bl + 1; g <= NG; ++g) gstart[g] = N;
    } else {
        int bp = batch[n - 1], bc = batch[n];
        for (int g = bp + 1; g <= bc; ++g) gstart[g] = n;
    }
}

__global__ void pool_kernel(const float* __restrict__ h5, const int* __restrict__ gstart,
                            float* __restrict__ pooled) {
    int g = blockIdx.x, c = threadIdx.x;  // 256 threads
    int s = gstart[g], e = gstart[g + 1];
    float sum = 0.f;
    for (int n = s; n < e; ++n) sum += h5[(size_t)n * 256 + c];
    float cnt = fmaxf((float)(e - s), 1.f);
    pooled[g * 256 + c] = elu_f(sum / cnt);
}

__global__ void linear_kernel(const float* __restrict__ pooled, const float* __restrict__ W,
                              const float* __restrict__ b, float* __restrict__ out) {
    int g = blockIdx.x, c = threadIdx.x;  // 128 threads
    float s = b[c];
    for (int k = 0; k < 256; ++k) s += pooled[g * 256 + k] * W[k * 128 + c];
    out[g * 128 + c] = s;
}

// ---------------- fused pool + linear (path 3) ----------------
__device__ __forceinline__ int lb_dev(const int* a, int n, int key) {
    int lo = 0, hi = n;
    while (lo < hi) { int mid = (lo + hi) >> 1; if (a[mid] < key) lo = mid + 1; else hi = mid; }
    return lo;
}

__global__ __launch_bounds__(256) void pool_linear_kernel(const float* __restrict__ h5,
                                                          const int* __restrict__ batch, int N,
                                                          const float* __restrict__ Wlin,
                                                          const float* __restrict__ blin,
                                                          float* __restrict__ out) {
    int g = blockIdx.x, c = threadIdx.x;
    int s = lb_dev(batch, N, g);
    int e = lb_dev(batch, N, g + 1);
    __shared__ float pooled_s[256];
    float sum = 0.f;
    for (int n = s; n < e; ++n) sum += h5[(size_t)n * 256 + c];
    float cnt = fmaxf((float)(e - s), 1.f);
    pooled_s[c] = elu_f(sum / cnt);
    __syncthreads();
    if (c < 128) {
        float acc = blin[c];
        for (int k = 0; k < 256; ++k) acc += pooled_s[k] * Wlin[k * 128 + c];
        out[g * 128 + c] = acc;
    }
}

// ---------------- fallback pipeline (VALU GEMM, typed) ----------------
template <typename TIO, typename TH>
static void run_pipeline(const float* x, const float* const* W, const float* const* asrc,
                         const float* const* adst, const float* const* bias,
                         char* rawIO, char* rawHT,
                         float* al_s, float* al_d, float* alpha_buf,
                         const int* offsets, const int* perm_src,
                         int N, hipStream_t stream) {
    TIO* bufIO = (TIO*)rawIO;
    TH*  bufHT = (TH*)rawHT;
    {
        dim3 g(512 / 64, (N + 63) / 64);
        gemm_kernel<float, TH><<<g, 256, 0, stream>>>(x, W[0], bufHT, N, 512, 128);
        al_kernel<TH><<<(N * NHEADS * 64 + 255) / 256, 256, 0, stream>>>(bufHT, asrc[0], adst[0], al_s, al_d, N, 64);
        alpha_kernel<<<(N * NHEADS + 255) / 256, 256, 0, stream>>>(offsets, perm_src, al_s, al_d, alpha_buf, N);
        agg_kernel<512, 64, 0, TH, TIO><<<N, 256, 0, stream>>>(bufHT, alpha_buf, offsets, perm_src, bias[0], bufIO, N);
    }
    int Kdim = 512;
    for (int l = 1; l < 5; ++l) {
        dim3 g(2048 / 64, (N + 63) / 64);
        gemm_kernel<TIO, TH><<<g, 256, 0, stream>>>(bufIO, W[l], bufHT, N, 2048, Kdim);
        al_kernel<TH><<<(N * NHEADS * 64 + 255) / 256, 256, 0, stream>>>(bufHT, asrc[l], adst[l], al_s, al_d, N, 256);
        alpha_kernel<<<(N * NHEADS + 255) / 256, 256, 0, stream>>>(offsets, perm_src, al_s, al_d, alpha_buf, N);
        if (l < 4)
            agg_kernel<2048, 256, 0, TH, TIO><<<N, 256, 0, stream>>>(bufHT, alpha_buf, offsets, perm_src, bias[l], bufIO, N);
        else
            agg_kernel<2048, 256, 1, TH, float><<<N, 256, 0, stream>>>(bufHT, alpha_buf, offsets, perm_src, bias[l], (float*)rawIO, N);
        Kdim = 2048;
    }
}

// ---------------- host ----------------
extern "C" void kernel_launch(void* const* d_in, const int* in_sizes, int n_in,
                              void* d_out, int out_size, void* d_ws, size_t ws_size,
                              hipStream_t stream) {
    const float* x     = (const float*)d_in[0];
    const int*   ei    = (const int*)d_in[1];
    const int*   batch = (const int*)d_in[2];
    const float* W[5]    = {(const float*)d_in[3],  (const float*)d_in[7],  (const float*)d_in[11],
                            (const float*)d_in[15], (const float*)d_in[19]};
    const float* asrc[5] = {(const float*)d_in[4],  (const float*)d_in[8],  (const float*)d_in[12],
                            (const float*)d_in[16], (const float*)d_in[20]};
    const float* adst[5] = {(const float*)d_in[5],  (const float*)d_in[9],  (const float*)d_in[13],
                            (const float*)d_in[17], (const float*)d_in[21]};
    const float* bias[5] = {(const float*)d_in[6],  (const float*)d_in[10], (const float*)d_in[14],
                            (const float*)d_in[18], (const float*)d_in[22]};
    const float* Wlin = (const float*)d_in[23];
    const float* blin = (const float*)d_in[24];

    const int N    = in_sizes[0] / 128;
    const int E    = in_sizes[1] / 2;
    const int Etot = E + N;

    auto align256 = [](size_t b) { return (b + 255) & ~(size_t)255; };

    size_t sz_counts = align256((size_t)N * 4);
    size_t sz_off    = align256((size_t)(N + 1) * 4);
    size_t sz_cur    = align256((size_t)N * 4);
    size_t sz_perm   = align256((size_t)Etot * 4);
    size_t sz_al     = align256((size_t)N * NHEADS * 4);
    size_t sz_alpha  = align256((size_t)Etot * NHEADS * 4);
    size_t sz_gst    = align256((size_t)(NG + 1) * 4);
    size_t sz_pool   = align256((size_t)NG * 256 * 4);
    size_t misc = sz_counts + sz_off + sz_cur + sz_perm + 2 * sz_al + sz_alpha + sz_gst + sz_pool;

    size_t bigf  = align256((size_t)N * 2048 * sizeof(float));
    size_t bigh  = align256((size_t)N * 2048 * sizeof(__half));
    const int Kd[5] = {128, 512, 2048, 2048, 2048};
    const int Nd[5] = {512, 2048, 2048, 2048, 2048};
    size_t sz_wt_each[5], sz_wt_all = 0;
    for (int l = 0; l < 5; ++l) { sz_wt_each[l] = align256((size_t)Kd[l] * Nd[l] * sizeof(__half)); sz_wt_all += sz_wt_each[l]; }
    size_t sz_x16 = align256((size_t)N * 128 * sizeof(__half));

    int path;
    if      (ws_size >= misc + 2 * bigh + sz_wt_all + sz_x16) path = 3;  // MFMA fp16 pipeline
    else if (ws_size >= misc + 2 * bigf)                      path = 0;
    else if (ws_size >= misc + bigf + bigh)                   path = 1;
    else if (ws_size >= misc + 2 * bigh)                      path = 2;
    else {
        hipMemsetAsync(d_out, 0, (size_t)out_size * sizeof(float), stream);
        return;
    }

    char* ws = (char*)d_ws;
    size_t off = 0;
    auto carve = [&](size_t bytes) { void* p = ws + off; off += bytes; return p; };
    int*   counts   = (int*)carve(sz_counts);
    int*   offsets  = (int*)carve(sz_off);
    int*   cursor   = (int*)carve(sz_cur);
    int*   perm_src = (int*)carve(sz_perm);
    float* al_s     = (float*)carve(sz_al);
    float* al_d     = (float*)carve(sz_al);
    float* alpha    = (float*)carve(sz_alpha);
    int*   gstart   = (int*)carve(sz_gst);
    float* pooled   = (float*)carve(sz_pool);

    // CSR build
    hipMemsetAsync(counts, 0, (size_t)N * 4, stream);
    hist_kernel<<<(Etot + 255) / 256, 256, 0, stream>>>(ei, E, Etot, counts);
    scan_kernel<<<1, 256, 0, stream>>>(counts, offsets, cursor, N);
    scatter_kernel<<<(Etot + 255) / 256, 256, 0, stream>>>(ei, E, Etot, cursor, perm_src);

    if (path == 3) {
        char*   rawIO = (char*)carve(bigh);
        char*   rawHT = (char*)carve(bigh);
        __half* Wt[5];
        for (int l = 0; l < 5; ++l) Wt[l] = (__half*)carve(sz_wt_each[l]);
        __half* x16   = (__half*)carve(sz_x16);
        __half* bufIO = (__half*)rawIO;
        __half* bufHT = (__half*)rawHT;

        // fused prep: x->fp16 + all 5 weight transposes
        PrepArgs pa;
        pa.x = x; pa.x16 = x16; pa.n4 = (long)N * 128 / 4;
        for (int l = 0; l < 5; ++l) { pa.W[l] = W[l]; pa.T[l] = Wt[l]; pa.K[l] = Kd[l]; pa.Nn[l] = Nd[l]; }
        int bacc = (int)((pa.n4 + 255) / 256);
        pa.b0 = bacc;
        for (int l = 0; l < 5; ++l) { bacc += (Nd[l] / 32) * (Kd[l] / 32); pa.tb[l] = bacc; }
        prep_kernel<<<bacc, 256, 0, stream>>>(pa);

        const __half* curA = x16;
        int Kdim = 128;
        for (int l = 0; l < 5; ++l) {
            const int C  = (l == 0) ? 64 : 256;
            const int HC = NHEADS * C;
            dim3 gg(HC / 256, (N + 255) / 256);
            if (l == 0) {
                gemm_mfma256_kernel<false><<<gg, 512, 0, stream>>>(curA, Wt[l], bufHT,
                                                                   nullptr, nullptr, nullptr, nullptr,
                                                                   N, HC, Kdim);
                al_vec_kernel<64><<<(N * NHEADS * 64 + 255) / 256, 256, 0, stream>>>(bufHT, asrc[l], adst[l], al_s, al_d, N);
            } else {
                gemm_mfma256_kernel<true><<<gg, 512, 0, stream>>>(curA, Wt[l], bufHT,
                                                                  asrc[l], adst[l], al_s, al_d,
                                                                  N, HC, Kdim);
            }
            if (l == 0)
                agg_fused_kernel<512, 64, 0><<<N, 256, 0, stream>>>(bufHT, al_s, al_d, offsets, perm_src, bias[l], bufIO, N);
            else if (l < 4)
                agg_fused_kernel<2048, 256, 0><<<N, 256, 0, stream>>>(bufHT, al_s, al_d, offsets, perm_src, bias[l], bufIO, N);
            else
                agg_fused_kernel<2048, 256, 1><<<N, 256, 0, stream>>>(bufHT, al_s, al_d, offsets, perm_src, bias[l], (float*)rawIO, N);
            curA = bufIO;
            Kdim = (l == 0) ? 512 : 2048;
        }
        pool_linear_kernel<<<NG, 256, 0, stream>>>((const float*)rawIO, batch, N, Wlin, blin, (float*)d_out);
        return;
    }

    char* rawIO = (char*)carve(path == 2 ? bigh : bigf);
    char* rawHT = (char*)carve(path == 0 ? bigf : bigh);

    if (path == 0)
        run_pipeline<float, float>(x, W, asrc, adst, bias, rawIO, rawHT, al_s, al_d, alpha, offsets, perm_src, N, stream);
    else if (path == 1)
        run_pipeline<float, __half>(x, W, asrc, adst, bias, rawIO, rawHT, al_s, al_d, alpha, offsets, perm_src, N, stream);
    else
        run_pipeline<__half, __half>(x, W, asrc, adst, bias, rawIO, rawHT, al_s, al_d, alpha, offsets, perm_src, N, stream);

    gstart_kernel<<<(N + 1 + 255) / 256, 256, 0, stream>>>(batch, gstart, N);
    pool_kernel<<<NG, 256, 0, stream>>>((const float*)rawIO, gstart, pooled);
    linear_kernel<<<NG, 128, 0, stream>>>(pooled, Wlin, blin, (float*)d_out);
}

// Round 13
// 1163.500 us; speedup vs baseline: 1.0505x; 1.0505x over previous
//
#include <hip/hip_runtime.h>
#include <hip/hip_fp16.h>
#include <math.h>

#define NHEADS 8
#define NG 64

typedef _Float16 half8_t __attribute__((ext_vector_type(8)));
typedef _Float16 half4_t __attribute__((ext_vector_type(4)));
typedef float    float4_t __attribute__((ext_vector_type(4)));
typedef __attribute__((address_space(1))) const void g_void;
typedef __attribute__((address_space(3))) void l_void;

__device__ __forceinline__ float elu_f(float x)   { return x > 0.f ? x : expf(x) - 1.f; }
__device__ __forceinline__ float lrelu_f(float x) { return x >= 0.f ? x : 0.2f * x; }

// ---- typed 4-wide load/store + scalar converts (fp32 / fp16) ----
__device__ __forceinline__ float4 ld4(const float* p) { return *(const float4*)p; }
__device__ __forceinline__ float4 ld4(const __half* p) {
    const __half2* q = (const __half2*)p;
    __half2 a = q[0], b = q[1];
    return make_float4(__half2float(a.x), __half2float(a.y),
                       __half2float(b.x), __half2float(b.y));
}
__device__ __forceinline__ void st4(float* p, float4 v) { *(float4*)p = v; }
__device__ __forceinline__ void st4(__half* p, float4 v) {
    __half2 a, b;
    a.x = __float2half(v.x); a.y = __float2half(v.y);
    b.x = __float2half(v.z); b.y = __float2half(v.w);
    __half2* q = (__half2*)p; q[0] = a; q[1] = b;
}
__device__ __forceinline__ float scl(float v)  { return v; }
__device__ __forceinline__ float scl(__half v) { return __half2float(v); }
__device__ __forceinline__ void sst(float* p, float v)  { *p = v; }
__device__ __forceinline__ void sst(__half* p, float v) { *p = __float2half(v); }

struct h4s { __half a, b, c, d; };

// ---------------- CSR build (by dst) ----------------
__global__ void hist_kernel(const int* __restrict__ ei, int E, int Etot, int* __restrict__ counts) {
    int e = blockIdx.x * blockDim.x + threadIdx.x;
    if (e >= Etot) return;
    int dst = (e < E) ? ei[E + e] : (e - E);   // self-loop for e >= E
    atomicAdd(&counts[dst], 1);
}

// single-block shuffle scan, 1024 elems/iter, 2 barriers/iter
__global__ __launch_bounds__(256) void scan_kernel(const int* __restrict__ counts,
                                                   int* __restrict__ offsets,
                                                   int* __restrict__ cursor, int N) {
    __shared__ int wsum[4];
    const int tid = threadIdx.x;
    const int lane = tid & 63, wid = tid >> 6;
    int carry = 0;
    for (int base = 0; base < N; base += 1024) {
        int i0 = base + tid * 4;
        int v0 = 0, v1 = 0, v2 = 0, v3 = 0;
        if (i0 + 3 < N) {
            int4 q = *(const int4*)(counts + i0);
            v0 = q.x; v1 = q.y; v2 = q.z; v3 = q.w;
        } else {
            if (i0     < N) v0 = counts[i0];
            if (i0 + 1 < N) v1 = counts[i0 + 1];
            if (i0 + 2 < N) v2 = counts[i0 + 2];
            if (i0 + 3 < N) v3 = counts[i0 + 3];
        }
        int tsum = v0 + v1 + v2 + v3;
        int incl = tsum;
#pragma unroll
        for (int off = 1; off < 64; off <<= 1) {
            int t = __shfl_up(incl, off);
            if (lane >= off) incl += t;
        }
        if (lane == 63) wsum[wid] = incl;
        __syncthreads();
        int woff = carry;
        for (int w = 0; w < wid; ++w) woff += wsum[w];
        int o0 = woff + incl - tsum;
        int o1 = o0 + v0, o2 = o1 + v1, o3 = o2 + v2;
        if (i0     < N) { offsets[i0]     = o0; cursor[i0]     = o0; }
        if (i0 + 1 < N) { offsets[i0 + 1] = o1; cursor[i0 + 1] = o1; }
        if (i0 + 2 < N) { offsets[i0 + 2] = o2; cursor[i0 + 2] = o2; }
        if (i0 + 3 < N) { offsets[i0 + 3] = o3; cursor[i0 + 3] = o3; }
        __syncthreads();
        carry += wsum[0] + wsum[1] + wsum[2] + wsum[3];
    }
    if (tid == 0) offsets[N] = carry;
}

__global__ void scatter_kernel(const int* __restrict__ ei, int E, int Etot,
                               int* __restrict__ cursor, int* __restrict__ perm_src) {
    int e = blockIdx.x * blockDim.x + threadIdx.x;
    if (e >= Etot) return;
    int src, dst;
    if (e < E) { src = ei[e]; dst = ei[E + e]; }
    else       { src = e - E; dst = e - E; }
    int pos = atomicAdd(&cursor[dst], 1);
    perm_src[pos] = src;
}

// ---------------- fused prep: x->fp16 convert + 5 weight transposes ----------------
struct PrepArgs {
    const float* x; __half* x16; long n4;
    const float* W[5]; __half* T[5];
    int K[5], Nn[5];
    int b0;          // end of convert stage
    int tb[5];       // cumulative ends of transpose stages
};

__global__ __launch_bounds__(256) void prep_kernel(PrepArgs a) {
    int bid = blockIdx.x;
    if (bid < a.b0) {
        long i = (long)bid * 256 + threadIdx.x;
        if (i < a.n4) {
            float4 v = ((const float4*)a.x)[i];
            h4s o; o.a = __float2half(v.x); o.b = __float2half(v.y);
            o.c = __float2half(v.z); o.d = __float2half(v.w);
            ((h4s*)a.x16)[i] = o;
        }
        return;
    }
    int l = 0, base = a.b0;
#pragma unroll
    for (int j = 0; j < 4; ++j) if (bid >= a.tb[j]) { l = j + 1; base = a.tb[j]; }
    const float* W = a.W[l]; __half* T = a.T[l];
    int K = a.K[l], Nn = a.Nn[l];
    int t = bid - base;
    int tilesx = Nn >> 5;
    int nb = (t % tilesx) * 32, kb = (t / tilesx) * 32;
    __shared__ float tt[32][33];
    int tx = threadIdx.x & 31, ty = threadIdx.x >> 5;
#pragma unroll
    for (int r = 0; r < 32; r += 8)
        tt[ty + r][tx] = W[(size_t)(kb + ty + r) * Nn + nb + tx];
    __syncthreads();
#pragma unroll
    for (int r = 0; r < 32; r += 8)
        T[(size_t)(nb + ty + r) * K + kb + tx] = __float2half(tt[tx][ty + r]);
}

// ---------------- 256x256 8-wave counted-vmcnt MFMA GEMM (R9 schedule) ----
// C[M][N] = A[M][K] @ Bt[N][K]^T, fp16 in, fp16 out, fp32 acc.
// BK=64, double-buffered LDS (128 KiB), 4 phases/K-tile (phase = C-quadrant),
// stage FIFO {A-lo,B-lo,B-hi,A-hi}, vmcnt(6) before P1/P2/P3.
// FUSE_AL epilogue: EXACT Round-11-benched version (reuses staging LDS after a
// vmcnt(0) drain + 2 syncthreads). NOTE: R12's "cleaner" dedicated 8KB al_sm
// pushed LDS to 136KiB and cost 13us/dispatch in the K-LOOP (MfmaUtil 36->33)
// — keep workgroup LDS at exactly 128KiB.
#define MMA_PHASE(MH, NH)                                                      \
  __builtin_amdgcn_s_setprio(1);                                               \
  { _Pragma("unroll") for (int f_ = 0; f_ < 4; ++f_) {                         \
      _Pragma("unroll") for (int g_ = 0; g_ < 2; ++g_) {                       \
        _Pragma("unroll") for (int kk_ = 0; kk_ < 2; ++kk_)                    \
          acc[(MH) * 2 + (NH)][f_][g_] =                                       \
              __builtin_amdgcn_mfma_f32_16x16x32_f16(                          \
                  af[f_][kk_], bf[g_][kk_],                                    \
                  acc[(MH) * 2 + (NH)][f_][g_], 0, 0, 0);                      \
  } } }                                                                        \
  __builtin_amdgcn_s_setprio(0);

template <bool FUSE_AL>
__global__ __launch_bounds__(512, 2) void gemm_mfma256_kernel(const __half* __restrict__ A,
                                                              const __half* __restrict__ Bt,
                                                              __half* __restrict__ C,
                                                              const float* __restrict__ a_src,
                                                              const float* __restrict__ a_dst,
                                                              float* __restrict__ al_s,
                                                              float* __restrict__ al_d,
                                                              int M, int N, int K) {
    __shared__ __half lds[2][2][16384];   // [buf][A=0/B=1][256*64]
    const int tid  = threadIdx.x;
    const int lane = tid & 63;
    const int wave = tid >> 6;            // 0..7
    const int wr   = wave >> 2;           // 0..1 (row half within quadrant)
    const int wc   = wave & 3;            // 0..3 (col quarter within quadrant)

    // XCD swizzle (bijective for any nwg)
    const int nwg = (int)(gridDim.x * gridDim.y);
    const int lin = (int)(blockIdx.y * gridDim.x + blockIdx.x);
    const int q = nwg >> 3, r = nwg & 7;
    const int xcd = lin & 7, idx = lin >> 3;
    const int nid = (xcd < r ? xcd * (q + 1) : r * (q + 1) + (xcd - r) * q) + idx;
    const int bx = nid % (int)gridDim.x;
    const int by = nid / (int)gridDim.x;
    const int row0 = by * 256;
    const int col0 = bx * 256;

    const int l15 = lane & 15, l4 = lane >> 4;
    const int srow = tid >> 3;                     // 0..63
    const int kch  = (tid & 7) ^ (srow & 7);       // XOR involution (stage source)

    float4_t acc[4][4][2];   // [quadrant mh*2+nh][m-frag][n-frag]
#pragma unroll
    for (int i = 0; i < 4; ++i)
#pragma unroll
        for (int j = 0; j < 4; ++j)
#pragma unroll
            for (int g = 0; g < 2; ++g)
                acc[i][j][g] = (float4_t){0.f, 0.f, 0.f, 0.f};

    // stage one half-tile (128 rows x 64 k) = 2 x global_load_lds per thread
    auto stageA = [&](int cb, int kt, int halfsel) {
#pragma unroll
        for (int sub = 0; sub < 2; ++sub) {
            int rr = halfsel * 128 + sub * 64 + srow;
            int gr = row0 + rr; if (gr >= M) gr = M - 1;    // clamp (stores guarded)
            const __half* g = A + (size_t)gr * K + kt * 64 + kch * 8;
            __half* l = &lds[cb][0][(halfsel * 128 + sub * 64) * 64] + tid * 8;
            __builtin_amdgcn_global_load_lds((g_void*)g, (l_void*)l, 16, 0, 0);
        }
    };
    auto stageB = [&](int cb, int kt, int halfsel) {
#pragma unroll
        for (int sub = 0; sub < 2; ++sub) {
            int rr = halfsel * 128 + sub * 64 + srow;
            const __half* g = Bt + (size_t)(col0 + rr) * K + kt * 64 + kch * 8;
            __half* l = &lds[cb][1][(halfsel * 128 + sub * 64) * 64] + tid * 8;
            __builtin_amdgcn_global_load_lds((g_void*)g, (l_void*)l, 16, 0, 0);
        }
    };

    half8_t af[4][2], bf[2][2];
    // phase-local fragment loads: quadrant (mh,nh) touches only A-half mh / B-half nh
    auto ldA = [&](int cb, int mh) {
        const char* base = (const char*)&lds[cb][0][0];
#pragma unroll
        for (int f = 0; f < 4; ++f) {
            int row = mh * 128 + wr * 64 + f * 16 + l15;   // within half mh
#pragma unroll
            for (int kk = 0; kk < 2; ++kk) {
                int ch = (kk * 4 + l4) ^ (row & 7);
                af[f][kk] = *(const half8_t*)(base + row * 128 + ch * 16);
            }
        }
    };
    auto ldB = [&](int cb, int nh) {
        const char* base = (const char*)&lds[cb][1][0];
#pragma unroll
        for (int f = 0; f < 2; ++f) {
            int row = nh * 128 + wc * 32 + f * 16 + l15;   // within half nh
#pragma unroll
            for (int kk = 0; kk < 2; ++kk) {
                int ch = (kk * 4 + l4) ^ (row & 7);
                bf[f][kk] = *(const half8_t*)(base + row * 128 + ch * 16);
            }
        }
    };

    const int nt = K >> 6;
    // prologue: tile 0 -> buf0, FIFO order A-lo, B-lo, B-hi, A-hi
    stageA(0, 0, 0); stageB(0, 0, 0); stageB(0, 0, 1); stageA(0, 0, 1);

    for (int t = 0; t < nt; ++t) {
        int cb = t & 1, nb = cb ^ 1;
        int ktn = (t + 1 < nt) ? t + 1 : t;   // last iter: clamped re-stage (never read)

        // P1: quadrant (0,0) — needs A-lo,B-lo of tile t (the 4 oldest loads)
        stageA(nb, ktn, 0);
        __builtin_amdgcn_sched_barrier(0);
        asm volatile("s_waitcnt vmcnt(6)" ::: "memory");
        __builtin_amdgcn_s_barrier();
        __builtin_amdgcn_sched_barrier(0);
        ldA(cb, 0); ldB(cb, 0);
        MMA_PHASE(0, 0)

        // P2: quadrant (0,1) — needs B-hi of tile t (af reused)
        stageB(nb, ktn, 0);
        __builtin_amdgcn_sched_barrier(0);
        asm volatile("s_waitcnt vmcnt(6)" ::: "memory");
        __builtin_amdgcn_s_barrier();
        __builtin_amdgcn_sched_barrier(0);
        ldB(cb, 1);
        MMA_PHASE(0, 1)

        // P3: quadrant (1,1) — needs A-hi of tile t (bf reused)
        stageB(nb, ktn, 1);
        __builtin_amdgcn_sched_barrier(0);
        asm volatile("s_waitcnt vmcnt(6)" ::: "memory");
        __builtin_amdgcn_s_barrier();
        __builtin_amdgcn_sched_barrier(0);
        ldA(cb, 1);
        MMA_PHASE(1, 1)

        // P4: quadrant (1,0) — all regions resident (B-lo re-read, af reused)
        stageA(nb, ktn, 1);
        ldB(cb, 0);
        MMA_PHASE(1, 0)
    }

    // C epilogue: C/D map col=lane&15, row=(lane>>4)*4+reg  [m89]
#pragma unroll
    for (int mh = 0; mh < 2; ++mh) {
#pragma unroll
        for (int nh = 0; nh < 2; ++nh) {
#pragma unroll
            for (int fm = 0; fm < 4; ++fm) {
#pragma unroll
                for (int r2 = 0; r2 < 4; ++r2) {
                    int row = row0 + mh * 128 + wr * 64 + fm * 16 + l4 * 4 + r2;
                    if (row < M) {
#pragma unroll
                        for (int fn = 0; fn < 2; ++fn) {
                            int col = col0 + nh * 128 + wc * 32 + fn * 16 + l15;
                            C[(size_t)row * N + col] = __float2half(acc[mh * 2 + nh][fm][fn][r2]);
                        }
                    }
                }
            }
        }
    }

    if constexpr (FUSE_AL) {
        // this block's 256 cols == head bx (N==2048, C==256). Compute exact
        // al_s/al_d for its rows from the fp32 accumulators. (R11-benched form.)
        const int h = bx;
        float as_v[2][2], ad_v[2][2];
#pragma unroll
        for (int nh = 0; nh < 2; ++nh)
#pragma unroll
            for (int fn = 0; fn < 2; ++fn) {
                int cc = nh * 128 + wc * 32 + fn * 16 + l15;
                as_v[nh][fn] = a_src[h * 256 + cc];
                ad_v[nh][fn] = a_dst[h * 256 + cc];
            }
        // drain the last garbage prefetch (async LDS writes!) before reusing LDS
        asm volatile("s_waitcnt vmcnt(0)" ::: "memory");
        __syncthreads();
        float* al_lds = (float*)&lds[0][0][0];   // [256 rows][4 wc][2] = 8 KB
#pragma unroll
        for (int mh = 0; mh < 2; ++mh)
#pragma unroll
            for (int fm = 0; fm < 4; ++fm)
#pragma unroll
                for (int r2 = 0; r2 < 4; ++r2) {
                    float ps = 0.f, pd = 0.f;
#pragma unroll
                    for (int nh = 0; nh < 2; ++nh)
#pragma unroll
                        for (int fn = 0; fn < 2; ++fn) {
                            float v = acc[mh * 2 + nh][fm][fn][r2];
                            ps += v * as_v[nh][fn];
                            pd += v * ad_v[nh][fn];
                        }
                    // reduce over the 16 lanes of this l4 group (l15 dimension)
#pragma unroll
                    for (int o = 1; o < 16; o <<= 1) {
                        ps += __shfl_xor(ps, o);
                        pd += __shfl_xor(pd, o);
                    }
                    if (l15 == 0) {
                        int rrow = mh * 128 + wr * 64 + fm * 16 + l4 * 4 + r2;
                        al_lds[(rrow * 4 + wc) * 2 + 0] = ps;
                        al_lds[(rrow * 4 + wc) * 2 + 1] = pd;
                    }
                }
        __syncthreads();
        if (tid < 256) {
            int grow = row0 + tid;
            if (grow < M) {
                float s = al_lds[(tid * 4 + 0) * 2] + al_lds[(tid * 4 + 1) * 2] +
                          al_lds[(tid * 4 + 2) * 2] + al_lds[(tid * 4 + 3) * 2];
                float d = al_lds[(tid * 4 + 0) * 2 + 1] + al_lds[(tid * 4 + 1) * 2 + 1] +
                          al_lds[(tid * 4 + 2) * 2 + 1] + al_lds[(tid * 4 + 3) * 2 + 1];
                al_s[(size_t)grow * 8 + h] = s;
                al_d[(size_t)grow * 8 + h] = d;
            }
        }
    }
}

// ---------------- VALU GEMM (fallback path): C[M,N] = A[M,K] @ B[K,N] ----------------
template <typename TA, typename TC>
__global__ __launch_bounds__(256) void gemm_kernel(const TA* __restrict__ A,
                                                   const float* __restrict__ B,
                                                   TC* __restrict__ C,
                                                   int M, int N, int K) {
    __shared__ float As[16][64];
    __shared__ float Bs[16][64];
    const int tid  = threadIdx.x;
    const int row0 = blockIdx.y * 64, col0 = blockIdx.x * 64;
    const int am = tid >> 2, ak = (tid & 3) << 2;
    const int bk = tid >> 4, bn = (tid & 15) << 2;
    const int ty = (tid >> 4) << 2, tx = (tid & 15) << 2;
    float acc[4][4] = {};
    const int arow = row0 + am;
    for (int k0 = 0; k0 < K; k0 += 16) {
        float4 a4 = make_float4(0.f, 0.f, 0.f, 0.f);
        if (arow < M) a4 = ld4(A + (size_t)arow * K + k0 + ak);
        As[ak + 0][am] = a4.x; As[ak + 1][am] = a4.y;
        As[ak + 2][am] = a4.z; As[ak + 3][am] = a4.w;
        *(float4*)&Bs[bk][bn] = *(const float4*)(B + (size_t)(k0 + bk) * N + col0 + bn);
        __syncthreads();
#pragma unroll
        for (int k = 0; k < 16; ++k) {
            float4 ar = *(const float4*)&As[k][ty];
            float4 br = *(const float4*)&Bs[k][tx];
            acc[0][0] += ar.x * br.x; acc[0][1] += ar.x * br.y; acc[0][2] += ar.x * br.z; acc[0][3] += ar.x * br.w;
            acc[1][0] += ar.y * br.x; acc[1][1] += ar.y * br.y; acc[1][2] += ar.y * br.z; acc[1][3] += ar.y * br.w;
            acc[2][0] += ar.z * br.x; acc[2][1] += ar.z * br.y; acc[2][2] += ar.z * br.z; acc[2][3] += ar.z * br.w;
            acc[3][0] += ar.w * br.x; acc[3][1] += ar.w * br.y; acc[3][2] += ar.w * br.z; acc[3][3] += ar.w * br.w;
        }
        __syncthreads();
    }
#pragma unroll
    for (int i = 0; i < 4; ++i) {
        int r = row0 + ty + i;
        if (r < M) {
            float4 o = make_float4(acc[i][0], acc[i][1], acc[i][2], acc[i][3]);
            st4(C + (size_t)r * N + col0 + tx, o);
        }
    }
}

// ---------------- l=0 attention logits: full-wave (4 pairs/wave, 16 lanes each) ----
__global__ void al_vec64_kernel(const __half* __restrict__ ht, const float* __restrict__ a_src,
                                const float* __restrict__ a_dst, float* __restrict__ al_s,
                                float* __restrict__ al_d, int N) {
    long wid  = (long)((blockIdx.x * blockDim.x + threadIdx.x) >> 6);
    int lane = threadIdx.x & 63;
    int sub = lane >> 4, l16 = lane & 15;
    long pair = wid * 4 + sub;
    if (pair >= (long)N * NHEADS) return;
    int n = (int)(pair >> 3), h = (int)(pair & 7);
    const __half* hp = ht + (size_t)n * 512 + h * 64 + l16 * 4;
    half4_t v = *(const half4_t*)hp;
    float4 as4 = *(const float4*)(a_src + h * 64 + l16 * 4);
    float4 ad4 = *(const float4*)(a_dst + h * 64 + l16 * 4);
    float v0 = (float)v[0], v1 = (float)v[1], v2 = (float)v[2], v3 = (float)v[3];
    float ss = v0 * as4.x + v1 * as4.y + v2 * as4.z + v3 * as4.w;
    float sd = v0 * ad4.x + v1 * ad4.y + v2 * ad4.z + v3 * ad4.w;
#pragma unroll
    for (int off = 8; off > 0; off >>= 1) {
        ss += __shfl_down(ss, off);
        sd += __shfl_down(sd, off);
    }
    if (l16 == 0) { al_s[pair] = ss; al_d[pair] = sd; }
}

// ---------------- aggregation with FUSED segment softmax ----------------
template <int HC, int C, int MODE>
__global__ __launch_bounds__(256) void agg_fused_kernel(const __half* __restrict__ ht,
                                                        const float* __restrict__ al_s,
                                                        const float* __restrict__ al_d,
                                                        const int* __restrict__ offsets,
                                                        const int* __restrict__ perm_src,
                                                        const float* __restrict__ bias,
                                                        void* __restrict__ outv, int N) {
    constexpr int V = HC / 256;          // 2 (HC=512) or 8 (HC=2048)
    int n = blockIdx.x;
    int tid = threadIdx.x;
    int lane = tid & 63;
    const int head = (tid * V) / C;      // constant per thread
    int s = offsets[n], e = offsets[n + 1];

    // per-wave softmax stats (redundant across the 4 waves)
    int h2 = lane & 7, es = lane >> 3;
    float ad2 = al_d[(size_t)n * 8 + h2];
    float m = -1e30f;
    for (int p0 = s + es; p0 < e; p0 += 8)
        m = fmaxf(m, lrelu_f(al_s[(size_t)perm_src[p0] * 8 + h2] + ad2));
#pragma unroll
    for (int off = 8; off < 64; off <<= 1) m = fmaxf(m, __shfl_xor(m, off));
    float den = 0.f;
    for (int p0 = s + es; p0 < e; p0 += 8)
        den += expf(lrelu_f(al_s[(size_t)perm_src[p0] * 8 + h2] + ad2) - m);
#pragma unroll
    for (int off = 8; off < 64; off <<= 1) den += __shfl_xor(den, off);
    float inv0 = 1.f / (den + 1e-16f);
    float mh   = __shfl(m, head);
    float invh = __shfl(inv0, head);
    float adh  = __shfl(ad2, head);

    float acc[V];
#pragma unroll
    for (int i = 0; i < V; ++i) acc[i] = 0.f;
    const __half* base = ht + (size_t)tid * V;
    int p = s;
    for (; p + 4 <= e; p += 4) {
        int s0 = perm_src[p], s1 = perm_src[p + 1], s2 = perm_src[p + 2], s3 = perm_src[p + 3];
        float a0 = expf(lrelu_f(al_s[(size_t)s0 * 8 + head] + adh) - mh);
        float a1 = expf(lrelu_f(al_s[(size_t)s1 * 8 + head] + adh) - mh);
        float a2 = expf(lrelu_f(al_s[(size_t)s2 * 8 + head] + adh) - mh);
        float a3 = expf(lrelu_f(al_s[(size_t)s3 * 8 + head] + adh) - mh);
        if (V == 8) {
            half8_t v0 = *(const half8_t*)(base + (size_t)s0 * HC);
            half8_t v1 = *(const half8_t*)(base + (size_t)s1 * HC);
            half8_t v2 = *(const half8_t*)(base + (size_t)s2 * HC);
            half8_t v3 = *(const half8_t*)(base + (size_t)s3 * HC);
#pragma unroll
            for (int i = 0; i < 8; ++i) acc[i] += a0 * (float)v0[i];
#pragma unroll
            for (int i = 0; i < 8; ++i) acc[i] += a1 * (float)v1[i];
#pragma unroll
            for (int i = 0; i < 8; ++i) acc[i] += a2 * (float)v2[i];
#pragma unroll
            for (int i = 0; i < 8; ++i) acc[i] += a3 * (float)v3[i];
        } else {
            __half2 w0 = *(const __half2*)(base + (size_t)s0 * HC);
            __half2 w1 = *(const __half2*)(base + (size_t)s1 * HC);
            __half2 w2 = *(const __half2*)(base + (size_t)s2 * HC);
            __half2 w3 = *(const __half2*)(base + (size_t)s3 * HC);
            acc[0] += a0 * __half2float(w0.x); acc[1] += a0 * __half2float(w0.y);
            acc[0] += a1 * __half2float(w1.x); acc[1] += a1 * __half2float(w1.y);
            acc[0] += a2 * __half2float(w2.x); acc[1] += a2 * __half2float(w2.y);
            acc[0] += a3 * __half2float(w3.x); acc[1] += a3 * __half2float(w3.y);
        }
    }
    for (; p < e; ++p) {
        int src = perm_src[p];
        float a = expf(lrelu_f(al_s[(size_t)src * 8 + head] + adh) - mh);
        const __half* hp = base + (size_t)src * HC;
        if (V == 8) {
            half8_t v = *(const half8_t*)hp;
#pragma unroll
            for (int i = 0; i < 8; ++i) acc[i] += a * (float)v[i];
        } else {
            __half2 v2 = *(const __half2*)hp;
            acc[0] += a * __half2float(v2.x);
            acc[1] += a * __half2float(v2.y);
        }
    }
    if (MODE == 0) {
        __half* out = (__half*)outv;
        if (V == 8) {
            half8_t o;
#pragma unroll
            for (int i = 0; i < 8; ++i)
                o[i] = (_Float16)elu_f(acc[i] * invh + bias[tid * 8 + i]);
            *(half8_t*)(out + (size_t)n * HC + tid * 8) = o;
        } else {
            __half2 o;
            o.x = __float2half(elu_f(acc[0] * invh + bias[tid * 2 + 0]));
            o.y = __float2half(elu_f(acc[1] * invh + bias[tid * 2 + 1]));
            *(__half2*)(out + (size_t)n * HC + tid * 2) = o;
        }
    } else {
        // V==8, C=256: LDS transpose-reduce over heads
        __shared__ float sm[256][8];
#pragma unroll
        for (int i = 0; i < 8; ++i) sm[tid][i] = acc[i] * invh;
        __syncthreads();
        float ssum = 0.f;
#pragma unroll
        for (int h = 0; h < 8; ++h) ssum += sm[h * 32 + (tid >> 3)][tid & 7];
        float* out = (float*)outv;
        out[(size_t)n * C + tid] = elu_f(ssum * (1.f / NHEADS) + bias[tid]);
    }
}

// ---------------- fallback scalar kernels (paths 0-2) ----------------
template <typename TH>
__global__ void al_kernel(const TH* __restrict__ ht, const float* __restrict__ a_src,
                          const float* __restrict__ a_dst, float* __restrict__ al_s,
                          float* __restrict__ al_d, int N, int C) {
    int wid  = (int)((blockIdx.x * blockDim.x + threadIdx.x) >> 6);
    int lane = threadIdx.x & 63;
    if (wid >= N * NHEADS) return;
    int n = wid / NHEADS, h = wid % NHEADS;
    const TH* hp = ht + (size_t)n * (NHEADS * C) + h * C;
    float ss = 0.f, sd = 0.f;
    for (int c = lane; c < C; c += 64) {
        float v = scl(hp[c]);
        ss += v * a_src[h * C + c];
        sd += v * a_dst[h * C + c];
    }
#pragma unroll
    for (int off = 32; off > 0; off >>= 1) {
        ss += __shfl_down(ss, off);
        sd += __shfl_down(sd, off);
    }
    if (lane == 0) { al_s[wid] = ss; al_d[wid] = sd; }
}

__global__ void alpha_kernel(const int* __restrict__ offsets, const int* __restrict__ perm_src,
                             const float* __restrict__ al_s, const float* __restrict__ al_d,
                             float* __restrict__ alpha, int N) {
    int idx = blockIdx.x * blockDim.x + threadIdx.x;
    if (idx >= N * NHEADS) return;
    int n = idx / NHEADS, h = idx % NHEADS;
    int s = offsets[n], e = offsets[n + 1];
    float ad = al_d[idx];
    float m = -1e30f;
    for (int p = s; p < e; ++p) {
        float v = lrelu_f(al_s[perm_src[p] * NHEADS + h] + ad);
        m = fmaxf(m, v);
    }
    float denom = 0.f;
    for (int p = s; p < e; ++p) {
        float v  = lrelu_f(al_s[perm_src[p] * NHEADS + h] + ad);
        float ex = expf(v - m);
        alpha[(size_t)p * NHEADS + h] = ex;
        denom += ex;
    }
    float inv = 1.f / (denom + 1e-16f);
    for (int p = s; p < e; ++p) alpha[(size_t)p * NHEADS + h] *= inv;
}

template <int HC, int C, int MODE, typename TH, typename TO>
__global__ __launch_bounds__(256) void agg_kernel(const TH* __restrict__ ht,
                                                  const float* __restrict__ alpha,
                                                  const int* __restrict__ offsets,
                                                  const int* __restrict__ perm_src,
                                                  const float* __restrict__ bias,
                                                  TO* __restrict__ out, int N) {
    constexpr int PER = HC / 256;
    int n = blockIdx.x;
    int tid = threadIdx.x;
    float acc[PER];
#pragma unroll
    for (int i = 0; i < PER; ++i) acc[i] = 0.f;
    int s = offsets[n], e = offsets[n + 1];
    for (int p = s; p < e; ++p) {
        int src = perm_src[p];
        const TH* hp = ht + (size_t)src * HC;
#pragma unroll
        for (int i = 0; i < PER; ++i) {
            int j = tid + i * 256;
            float a = alpha[(size_t)p * NHEADS + (j / C)];
            acc[i] += a * scl(hp[j]);
        }
    }
    if (MODE == 0) {
#pragma unroll
        for (int i = 0; i < PER; ++i) {
            int j = tid + i * 256;
            sst(&out[(size_t)n * HC + j], elu_f(acc[i] + bias[j]));
        }
    } else {
        float srow = 0.f;
#pragma unroll
        for (int i = 0; i < PER; ++i) srow += acc[i];
        sst(&out[(size_t)n * C + tid], elu_f(srow * (1.f / NHEADS) + bias[tid]));
    }
}

// ---------------- pooling (fallback path kernels) ----------------
__global__ void gstart_kernel(const int* __restrict__ batch, int* __restrict__ gstart, int N) {
    int n = blockIdx.x * blockDim.x + threadIdx.x;
    if (n > N) return;
    if (n == 0) {
        int b0 = batch[0];
        for (int g = 0; g <= b0; ++g) gstart[g] = 0;
    } else if (n == N) {
        int bl = batch[N - 1];
        for (int g = bl + 1; g <= NG; ++g) gstart[g] = N;
    } else {
        int bp = batch[n - 1], bc = batch[n];
        for (int g = bp + 1; g <= bc; ++g) gstart[g] = n;
    }
}

__global__ void pool_kernel(const float* __restrict__ h5, const int* __restrict__ gstart,
                            float* __restrict__ pooled) {
    int g = blockIdx.x, c = threadIdx.x;  // 256 threads
    int s = gstart[g], e = gstart[g + 1];
    float sum = 0.f;
    for (int n = s; n < e; ++n) sum += h5[(size_t)n * 256 + c];
    float cnt = fmaxf((float)(e - s), 1.f);
    pooled[g * 256 + c] = elu_f(sum / cnt);
}

__global__ void linear_kernel(const float* __restrict__ pooled, const float* __restrict__ W,
                              const float* __restrict__ b, float* __restrict__ out) {
    int g = blockIdx.x, c = threadIdx.x;  // 128 threads
    float s = b[c];
    for (int k = 0; k < 256; ++k) s += pooled[g * 256 + k] * W[k * 128 + c];
    out[g * 128 + c] = s;
}

// ---------------- fused pool + linear (path 3) ----------------
__device__ __forceinline__ int lb_dev(const int* a, int n, int key) {
    int lo = 0, hi = n;
    while (lo < hi) { int mid = (lo + hi) >> 1; if (a[mid] < key) lo = mid + 1; else hi = mid; }
    return lo;
}

__global__ __launch_bounds__(256) void pool_linear_kernel(const float* __restrict__ h5,
                                                          const int* __restrict__ batch, int N,
                                                          const float* __restrict__ Wlin,
                                                          const float* __restrict__ blin,
                                                          float* __restrict__ out) {
    int g = blockIdx.x, c = threadIdx.x;
    int s = lb_dev(batch, N, g);
    int e = lb_dev(batch, N, g + 1);
    __shared__ float pooled_s[256];
    float sum = 0.f;
    for (int n = s; n < e; ++n) sum += h5[(size_t)n * 256 + c];
    float cnt = fmaxf((float)(e - s), 1.f);
    pooled_s[c] = elu_f(sum / cnt);
    __syncthreads();
    if (c < 128) {
        float acc = blin[c];
        for (int k = 0; k < 256; ++k) acc += pooled_s[k] * Wlin[k * 128 + c];
        out[g * 128 + c] = acc;
    }
}

// ---------------- fallback pipeline (VALU GEMM, typed) ----------------
template <typename TIO, typename TH>
static void run_pipeline(const float* x, const float* const* W, const float* const* asrc,
                         const float* const* adst, const float* const* bias,
                         char* rawIO, char* rawHT,
                         float* al_s, float* al_d, float* alpha_buf,
                         const int* offsets, const int* perm_src,
                         int N, hipStream_t stream) {
    TIO* bufIO = (TIO*)rawIO;
    TH*  bufHT = (TH*)rawHT;
    {
        dim3 g(512 / 64, (N + 63) / 64);
        gemm_kernel<float, TH><<<g, 256, 0, stream>>>(x, W[0], bufHT, N, 512, 128);
        al_kernel<TH><<<(N * NHEADS * 64 + 255) / 256, 256, 0, stream>>>(bufHT, asrc[0], adst[0], al_s, al_d, N, 64);
        alpha_kernel<<<(N * NHEADS + 255) / 256, 256, 0, stream>>>(offsets, perm_src, al_s, al_d, alpha_buf, N);
        agg_kernel<512, 64, 0, TH, TIO><<<N, 256, 0, stream>>>(bufHT, alpha_buf, offsets, perm_src, bias[0], bufIO, N);
    }
    int Kdim = 512;
    for (int l = 1; l < 5; ++l) {
        dim3 g(2048 / 64, (N + 63) / 64);
        gemm_kernel<TIO, TH><<<g, 256, 0, stream>>>(bufIO, W[l], bufHT, N, 2048, Kdim);
        al_kernel<TH><<<(N * NHEADS * 64 + 255) / 256, 256, 0, stream>>>(bufHT, asrc[l], adst[l], al_s, al_d, N, 256);
        alpha_kernel<<<(N * NHEADS + 255) / 256, 256, 0, stream>>>(offsets, perm_src, al_s, al_d, alpha_buf, N);
        if (l < 4)
            agg_kernel<2048, 256, 0, TH, TIO><<<N, 256, 0, stream>>>(bufHT, alpha_buf, offsets, perm_src, bias[l], bufIO, N);
        else
            agg_kernel<2048, 256, 1, TH, float><<<N, 256, 0, stream>>>(bufHT, alpha_buf, offsets, perm_src, bias[l], (float*)rawIO, N);
        Kdim = 2048;
    }
}

// ---------------- host ----------------
extern "C" void kernel_launch(void* const* d_in, const int* in_sizes, int n_in,
                              void* d_out, int out_size, void* d_ws, size_t ws_size,
                              hipStream_t stream) {
    const float* x     = (const float*)d_in[0];
    const int*   ei    = (const int*)d_in[1];
    const int*   batch = (const int*)d_in[2];
    const float* W[5]    = {(const float*)d_in[3],  (const float*)d_in[7],  (const float*)d_in[11],
                            (const float*)d_in[15], (const float*)d_in[19]};
    const float* asrc[5] = {(const float*)d_in[4],  (const float*)d_in[8],  (const float*)d_in[12],
                            (const float*)d_in[16], (const float*)d_in[20]};
    const float* adst[5] = {(const float*)d_in[5],  (const float*)d_in[9],  (const float*)d_in[13],
                            (const float*)d_in[17], (const float*)d_in[21]};
    const float* bias[5] = {(const float*)d_in[6],  (const float*)d_in[10], (const float*)d_in[14],
                            (const float*)d_in[18], (const float*)d_in[22]};
    const float* Wlin = (const float*)d_in[23];
    const float* blin = (const float*)d_in[24];

    const int N    = in_sizes[0] / 128;
    const int E    = in_sizes[1] / 2;
    const int Etot = E + N;

    auto align256 = [](size_t b) { return (b + 255) & ~(size_t)255; };

    size_t sz_counts = align256((size_t)N * 4);
    size_t sz_off    = align256((size_t)(N + 1) * 4);
    size_t sz_cur    = align256((size_t)N * 4);
    size_t sz_perm   = align256((size_t)Etot * 4);
    size_t sz_al     = align256((size_t)N * NHEADS * 4);
    size_t sz_alpha  = align256((size_t)Etot * NHEADS * 4);
    size_t sz_gst    = align256((size_t)(NG + 1) * 4);
    size_t sz_pool   = align256((size_t)NG * 256 * 4);
    size_t misc = sz_counts + sz_off + sz_cur + sz_perm + 2 * sz_al + sz_alpha + sz_gst + sz_pool;

    size_t bigf  = align256((size_t)N * 2048 * sizeof(float));
    size_t bigh  = align256((size_t)N * 2048 * sizeof(__half));
    const int Kd[5] = {128, 512, 2048, 2048, 2048};
    const int Nd[5] = {512, 2048, 2048, 2048, 2048};
    size_t sz_wt_each[5], sz_wt_all = 0;
    for (int l = 0; l < 5; ++l) { sz_wt_each[l] = align256((size_t)Kd[l] * Nd[l] * sizeof(__half)); sz_wt_all += sz_wt_each[l]; }
    size_t sz_x16 = align256((size_t)N * 128 * sizeof(__half));

    int path;
    if      (ws_size >= misc + 2 * bigh + sz_wt_all + sz_x16) path = 3;  // MFMA fp16 pipeline
    else if (ws_size >= misc + 2 * bigf)                      path = 0;
    else if (ws_size >= misc + bigf + bigh)                   path = 1;
    else if (ws_size >= misc + 2 * bigh)                      path = 2;
    else {
        hipMemsetAsync(d_out, 0, (size_t)out_size * sizeof(float), stream);
        return;
    }

    char* ws = (char*)d_ws;
    size_t off = 0;
    auto carve = [&](size_t bytes) { void* p = ws + off; off += bytes; return p; };
    int*   counts   = (int*)carve(sz_counts);
    int*   offsets  = (int*)carve(sz_off);
    int*   cursor   = (int*)carve(sz_cur);
    int*   perm_src = (int*)carve(sz_perm);
    float* al_s     = (float*)carve(sz_al);
    float* al_d     = (float*)carve(sz_al);
    float* alpha    = (float*)carve(sz_alpha);
    int*   gstart   = (int*)carve(sz_gst);
    float* pooled   = (float*)carve(sz_pool);

    // CSR build
    hipMemsetAsync(counts, 0, (size_t)N * 4, stream);
    hist_kernel<<<(Etot + 255) / 256, 256, 0, stream>>>(ei, E, Etot, counts);
    scan_kernel<<<1, 256, 0, stream>>>(counts, offsets, cursor, N);
    scatter_kernel<<<(Etot + 255) / 256, 256, 0, stream>>>(ei, E, Etot, cursor, perm_src);

    if (path == 3) {
        char*   rawIO = (char*)carve(bigh);
        char*   rawHT = (char*)carve(bigh);
        __half* Wt[5];
        for (int l = 0; l < 5; ++l) Wt[l] = (__half*)carve(sz_wt_each[l]);
        __half* x16   = (__half*)carve(sz_x16);
        __half* bufIO = (__half*)rawIO;
        __half* bufHT = (__half*)rawHT;

        // fused prep: x->fp16 + all 5 weight transposes
        PrepArgs pa;
        pa.x = x; pa.x16 = x16; pa.n4 = (long)N * 128 / 4;
        for (int l = 0; l < 5; ++l) { pa.W[l] = W[l]; pa.T[l] = Wt[l]; pa.K[l] = Kd[l]; pa.Nn[l] = Nd[l]; }
        int bacc = (int)((pa.n4 + 255) / 256);
        pa.b0 = bacc;
        for (int l = 0; l < 5; ++l) { bacc += (Nd[l] / 32) * (Kd[l] / 32); pa.tb[l] = bacc; }
        prep_kernel<<<bacc, 256, 0, stream>>>(pa);

        const __half* curA = x16;
        int Kdim = 128;
        for (int l = 0; l < 5; ++l) {
            const int C  = (l == 0) ? 64 : 256;
            const int HC = NHEADS * C;
            dim3 gg(HC / 256, (N + 255) / 256);
            if (l == 0) {
                gemm_mfma256_kernel<false><<<gg, 512, 0, stream>>>(curA, Wt[l], bufHT,
                                                                   nullptr, nullptr, nullptr, nullptr,
                                                                   N, HC, Kdim);
                al_vec64_kernel<<<(N * NHEADS * 16 + 255) / 256, 256, 0, stream>>>(bufHT, asrc[l], adst[l], al_s, al_d, N);
            } else {
                gemm_mfma256_kernel<true><<<gg, 512, 0, stream>>>(curA, Wt[l], bufHT,
                                                                  asrc[l], adst[l], al_s, al_d,
                                                                  N, HC, Kdim);
            }
            if (l == 0)
                agg_fused_kernel<512, 64, 0><<<N, 256, 0, stream>>>(bufHT, al_s, al_d, offsets, perm_src, bias[l], bufIO, N);
            else if (l < 4)
                agg_fused_kernel<2048, 256, 0><<<N, 256, 0, stream>>>(bufHT, al_s, al_d, offsets, perm_src, bias[l], bufIO, N);
            else
                agg_fused_kernel<2048, 256, 1><<<N, 256, 0, stream>>>(bufHT, al_s, al_d, offsets, perm_src, bias[l], (float*)rawIO, N);
            curA = bufIO;
            Kdim = (l == 0) ? 512 : 2048;
        }
        pool_linear_kernel<<<NG, 256, 0, stream>>>((const float*)rawIO, batch, N, Wlin, blin, (float*)d_out);
        return;
    }

    char* rawIO = (char*)carve(path == 2 ? bigh : bigf);
    char* rawHT = (char*)carve(path == 0 ? bigf : bigh);

    if (path == 0)
        run_pipeline<float, float>(x, W, asrc, adst, bias, rawIO, rawHT, al_s, al_d, alpha, offsets, perm_src, N, stream);
    else if (path == 1)
        run_pipeline<float, __half>(x, W, asrc, adst, bias, rawIO, rawHT, al_s, al_d, alpha, offsets, perm_src, N, stream);
    else
        run_pipeline<__half, __half>(x, W, asrc, adst, bias, rawIO, rawHT, al_s, al_d, alpha, offsets, perm_src, N, stream);

    gstart_kernel<<<(N + 1 + 255) / 256, 256, 0, stream>>>(batch, gstart, N);
    pool_kernel<<<NG, 256, 0, stream>>>((const float*)rawIO, gstart, pooled);
    linear_kernel<<<NG, 128, 0, stream>>>(pooled, Wlin, blin, (float*)d_out);
}